// Round 3
// baseline (448.822 us; speedup 1.0000x reference)
//
#include <hip/hip_runtime.h>

// Subtractor50Bit: A - B via two's complement, N rows x 50 bits ({0,1} floats).
// out = [result (N*50 floats), borrow (N floats)].
//
// R4: LDS-staged, ballot-free rewrite.
// R1-R3 post-mortem: three different register-staged ballot kernels all
// plateau at ~155us with NOTHING saturated (VALU 16%, HBM 32%, DS ~0) --
// waves spend ~70K cycles stalled because the in-flight window lives in
// VGPRs and the register allocator keeps collapsing it (R3: VGPR=56 proves
// the 50-load window never materialized despite sched_barrier).
// Fix: stage tiles HBM->LDS with __builtin_amdgcn_global_load_lds (zero
// VGPR cost, 25.6KB/wave guaranteed in flight), then do the transpose by
// ADDRESSING: each lane ds_reads its own row from LDS (no ballot/shfl at
// all), packs bits, subtracts, unpacks, writes the row back to LDS, and
// the wave streams out coalesced 16B/lane float4 stores.
// One wave per block -> no barriers, only the wave's own vmcnt/lgkmcnt.
// Per-wave: VMEM 76->42 instrs, DS ~63, VALU ~450. LDS 25.6KB -> 6 blocks/CU.

constexpr int BITS = 50;
constexpr unsigned long long MASK50 = (1ULL << BITS) - 1ULL;

// HBM -> LDS direct copy, 16B per lane. LDS dest is wave-uniform base
// (HW writes base + lane*16); global src is per-lane.
__device__ __forceinline__ void gl_lds16(const float* g, float* l) {
    __builtin_amdgcn_global_load_lds(
        (const __attribute__((address_space(1))) void*)g,
        (__attribute__((address_space(3))) void*)l, 16, 0, 0);
}
// 4B-per-lane variant for the 512B tile tail.
__device__ __forceinline__ void gl_lds4(const float* g, float* l) {
    __builtin_amdgcn_global_load_lds(
        (const __attribute__((address_space(1))) void*)g,
        (__attribute__((address_space(3))) void*)l, 4, 0, 0);
}

__global__ __launch_bounds__(64) void Subtractor50Bit_kernel(
    const float* __restrict__ A, const float* __restrict__ B,
    float* __restrict__ out, int N)
{
    __shared__ float sA[3200];   // 64 rows x 50 floats = 12.8 KB
    __shared__ float sB[3200];   // 12.8 KB  (sA reused for the result)

    const int lane = threadIdx.x;            // 64-thread block = 1 wave
    const long long rowBase = (long long)blockIdx.x * 64;
    if (rowBase >= N) return;

    if (rowBase + 64 <= N) {
        const long long eBase = rowBase * BITS;        // 3200 floats/tile
        const float* ga = A + eBase;
        const float* gb = B + eBase;

        // ---- Phase 1: async-stage both tiles into LDS (no VGPR cost).
        // 12 x 1KB + 2 x 256B per operand; 28 loads, 25.6KB in flight.
        #pragma unroll
        for (int j = 0; j < 12; ++j) gl_lds16(ga + 256 * j + 4 * lane, &sA[256 * j]);
        gl_lds4(ga + 3072 + lane, &sA[3072]);
        gl_lds4(ga + 3136 + lane, &sA[3136]);
        #pragma unroll
        for (int j = 0; j < 12; ++j) gl_lds16(gb + 256 * j + 4 * lane, &sB[256 * j]);
        gl_lds4(gb + 3072 + lane, &sB[3072]);
        gl_lds4(gb + 3136 + lane, &sB[3136]);

        // Wait for the async copies; fence so LDS reads can't hoist above.
        asm volatile("s_waitcnt vmcnt(0)" ::: "memory");
        __builtin_amdgcn_sched_barrier(0);

        // ---- Phase 2: lane owns row (rowBase+lane): read 50 floats from
        // LDS (8B-aligned float2, stride-50 rows -> ~4-way bank alias, ok),
        // pack to a 50-bit integer. 1.0f has bit23 set; inputs are exact
        // {0.0f, 1.0f}.
        const float2* rA = (const float2*)sA + 25 * lane;
        const float2* rB = (const float2*)sB + 25 * lane;
        unsigned alo = 0, ahi = 0, blo = 0, bhi = 0;
        #pragma unroll
        for (int j = 0; j < 25; ++j) {
            float2 va = rA[j];
            float2 vb = rB[j];
            unsigned a0 = (__float_as_uint(va.x) >> 23) & 1u;
            unsigned a1 = (__float_as_uint(va.y) >> 23) & 1u;
            unsigned b0 = (__float_as_uint(vb.x) >> 23) & 1u;
            unsigned b1 = (__float_as_uint(vb.y) >> 23) & 1u;
            if (j < 16) {                    // bits 2j, 2j+1 in [0,32)
                alo |= a0 << (2 * j); alo |= a1 << (2 * j + 1);
                blo |= b0 << (2 * j); blo |= b1 << (2 * j + 1);
            } else {                         // bits in [32,50)
                ahi |= a0 << (2 * j - 32); ahi |= a1 << (2 * j - 31);
                bhi |= b0 << (2 * j - 32); bhi |= b1 << (2 * j - 31);
            }
        }
        unsigned long long av = ((unsigned long long)ahi << 32) | alo;
        unsigned long long bv = ((unsigned long long)bhi << 32) | blo;

        unsigned long long diff = (av - bv) & MASK50;  // A + ~B + 1 (mod 2^50)
        float borrow = (av < bv) ? 1.0f : 0.0f;        // 1 - carry_out

        // ---- Phase 3: unpack result bits to floats, row back into sA.
        float2* wO = (float2*)sA + 25 * lane;
        #pragma unroll
        for (int j = 0; j < 25; ++j) {
            float2 o;
            o.x = (float)(unsigned)((diff >> (2 * j)) & 1ULL);
            o.y = (float)(unsigned)((diff >> (2 * j + 1)) & 1ULL);
            wO[j] = o;
        }

        // ---- Phase 4: coalesced wide stores straight from LDS.
        // (Same wave wrote all rows; compiler's lgkmcnt wait on sA orders
        // the cross-lane reads -- no barrier needed with one wave/block.)
        const float4* sO4 = (const float4*)sA;
        float4* go4 = (float4*)(out + eBase);
        #pragma unroll
        for (int j = 0; j < 12; ++j) go4[64 * j + lane] = sO4[64 * j + lane];
        const float2* sO2 = (const float2*)(sA + 3072);
        float2* go2 = (float2*)(out + eBase + 3072);
        go2[lane] = sO2[lane];

        // borrow segment: naturally coalesced
        out[(long long)N * BITS + rowBase + lane] = borrow;
    } else {
        // ---- scalar tail path (partial wave; N%64!=0 safety net) ----
        long long r = rowBase + lane;
        if (r < N) {
            unsigned long long av = 0, bv = 0;
            for (int k = 0; k < BITS; ++k) {
                av |= (unsigned long long)(A[r * BITS + k] != 0.0f) << k;
                bv |= (unsigned long long)(B[r * BITS + k] != 0.0f) << k;
            }
            unsigned long long diff = (av - bv) & MASK50;
            for (int k = 0; k < BITS; ++k)
                out[r * BITS + k] = (float)((diff >> k) & 1ULL);
            out[(long long)N * BITS + r] = (av < bv) ? 1.0f : 0.0f;
        }
    }
}

extern "C" void kernel_launch(void* const* d_in, const int* in_sizes, int n_in,
                              void* d_out, int out_size, void* d_ws, size_t ws_size,
                              hipStream_t stream) {
    const float* A = (const float*)d_in[0];
    const float* B = (const float*)d_in[1];
    float* out = (float*)d_out;
    const int N = in_sizes[0] / BITS;          // 1,000,000

    const int blocks = (N + 63) / 64;          // one 64-thread wave per 64 rows
    Subtractor50Bit_kernel<<<blocks, 64, 0, stream>>>(A, B, out, N);
}